// Round 10
// baseline (143.553 us; speedup 1.0000x reference)
//
#include <hip/hip_runtime.h>

#define TDIM 4096
#define BDIM 256
#define ADIM 26
#define SDIM 4
#define LCH 16
#define CCH 256
#define NEGF -1e30f
#define LOG2E 1.44269504088896340736f

__device__ __forceinline__ float ex2(float x) { return __builtin_amdgcn_exp2f(x); }
__device__ __forceinline__ float lg2(float x) { return __builtin_amdgcn_logf(x); }

__device__ __forceinline__ float l2se2(float a, float b) {
    float mx = fmaxf(a, b), mn = fminf(a, b);
    return mx + lg2(1.f + ex2(mn - mx));
}
__device__ __forceinline__ float l2se3(float a, float b, float c) {
    float mx = fmaxf(fmaxf(a, b), c);
    float md = __builtin_amdgcn_fmed3f(a, b, c);
    float mn = fminf(fminf(a, b), c);
    return mx + lg2(1.f + ex2(md - mx) + ex2(mn - mx));
}
__device__ __forceinline__ float l2se4(float a, float b, float c, float d) {
    float h1 = fmaxf(a, b), l1 = fminf(a, b);
    float h2 = fmaxf(c, d), l2 = fminf(c, d);
    float mx = fmaxf(h1, h2), s2 = fminf(h1, h2);
    return mx + lg2(1.f + ex2(s2 - mx) + ex2(l1 - mx) + ex2(l2 - mx));
}

struct TransA { float A00, A01, A02, A11, A12, A13, A22, A23, A33; };

__device__ __forceinline__ TransA make_transA(const float* __restrict__ trans) {
    TransA A;
    {
        float l0 = trans[0], l1 = trans[1], l2 = trans[2];
        float m = fmaxf(fmaxf(l0, l1), l2);
        float lz = m + __logf(__expf(l0 - m) + __expf(l1 - m) + __expf(l2 - m));
        A.A00 = (l0 - lz) * LOG2E; A.A01 = (l1 - lz) * LOG2E; A.A02 = (l2 - lz) * LOG2E;
    }
    {
        float l1 = trans[5], l2 = trans[6], l3 = trans[7];
        float m = fmaxf(fmaxf(l1, l2), l3);
        float lz = m + __logf(__expf(l1 - m) + __expf(l2 - m) + __expf(l3 - m));
        A.A11 = (l1 - lz) * LOG2E; A.A12 = (l2 - lz) * LOG2E; A.A13 = (l3 - lz) * LOG2E;
    }
    {
        float l2 = trans[10], l3 = trans[11];
        float m = fmaxf(l2, l3);
        float lz = m + __logf(__expf(l2 - m) + __expf(l3 - m));
        A.A22 = (l2 - lz) * LOG2E; A.A23 = (l3 - lz) * LOG2E;
    }
    A.A33 = 0.f;
    return A;
}

struct UT { float m00, m01, m02, m03, m11, m12, m13, m22, m23, m33; };

__device__ __forceinline__ void fstep(UT& M, const TransA& A, float4 e) {
    float n00 = M.m00 + A.A00 + e.x;
    float n01 = l2se2(M.m00 + A.A01, M.m01 + A.A11) + e.y;
    float n02 = l2se3(M.m00 + A.A02, M.m01 + A.A12, M.m02 + A.A22) + e.z;
    float n03 = l2se3(M.m01 + A.A13, M.m02 + A.A23, M.m03) + e.w;
    float n11 = M.m11 + A.A11 + e.y;
    float n12 = l2se2(M.m11 + A.A12, M.m12 + A.A22) + e.z;
    float n13 = l2se3(M.m11 + A.A13, M.m12 + A.A23, M.m13) + e.w;
    float n22 = M.m22 + A.A22 + e.z;
    float n23 = l2se2(M.m22 + A.A23, M.m23) + e.w;
    float n33 = M.m33 + e.w;
    M.m00 = n00; M.m01 = n01; M.m02 = n02; M.m03 = n03;
    M.m11 = n11; M.m12 = n12; M.m13 = n13; M.m22 = n22; M.m23 = n23; M.m33 = n33;
}

// C = A (x) B in log-semiring (row-vec convention: v (x) C == (v (x) A) (x) B)
__device__ __forceinline__ UT ut_compose(const UT& A, const UT& B) {
    UT C;
    C.m00 = A.m00 + B.m00;
    C.m01 = l2se2(A.m00 + B.m01, A.m01 + B.m11);
    C.m02 = l2se3(A.m00 + B.m02, A.m01 + B.m12, A.m02 + B.m22);
    C.m03 = l2se4(A.m00 + B.m03, A.m01 + B.m13, A.m02 + B.m23, A.m03 + B.m33);
    C.m11 = A.m11 + B.m11;
    C.m12 = l2se2(A.m11 + B.m12, A.m12 + B.m22);
    C.m13 = l2se3(A.m11 + B.m13, A.m12 + B.m23, A.m13 + B.m33);
    C.m22 = A.m22 + B.m22;
    C.m23 = l2se2(A.m22 + B.m23, A.m23 + B.m33);
    C.m33 = A.m33 + B.m33;
    return C;
}

__device__ __forceinline__ void ut_renorm(UT& M) {
    float m1 = fmaxf(fmaxf(M.m00, M.m01), fmaxf(M.m02, M.m03));
    float m2 = fmaxf(fmaxf(M.m11, M.m12), fmaxf(M.m13, M.m22));
    float m3 = fmaxf(M.m23, M.m33);
    float mx = fmaxf(fmaxf(m1, m2), m3);
    M.m00 -= mx; M.m01 -= mx; M.m02 -= mx; M.m03 -= mx;
    M.m11 -= mx; M.m12 -= mx; M.m13 -= mx; M.m22 -= mx; M.m23 -= mx; M.m33 -= mx;
}

__device__ __forceinline__ void ut_store(float* p, const UT& M) {
    p[0] = M.m00; p[1] = M.m01; p[2] = M.m02; p[3] = M.m03;
    p[4] = M.m11; p[5] = M.m12; p[6] = M.m13;
    p[7] = M.m22; p[8] = M.m23; p[9] = M.m33;
}
__device__ __forceinline__ UT ut_load(const float* p) {
    UT M;
    M.m00 = p[0]; M.m01 = p[1]; M.m02 = p[2]; M.m03 = p[3];
    M.m11 = p[4]; M.m12 = p[5]; M.m13 = p[6];
    M.m22 = p[7]; M.m23 = p[8]; M.m33 = p[9];
    return M;
}

#define ASTEP(E) do { \
    float4 _e = (E); \
    float n0_ = a0 + A.A00; \
    float n1_ = l2se2(a0 + A.A01, a1 + A.A11); \
    float n2_ = l2se3(a0 + A.A02, a1 + A.A12, a2 + A.A22); \
    float n3_ = l2se3(a1 + A.A13, a2 + A.A23, a3); \
    a0 = n0_ + _e.x; a1 = n1_ + _e.y; a2 = n2_ + _e.z; a3 = n3_ + _e.w; \
    float mm_ = fmaxf(fmaxf(a0, a1), fmaxf(a2, a3)); \
    a0 -= mm_; a1 -= mm_; a2 -= mm_; a3 -= mm_; \
} while (0)

#define BSTEP(E) do { \
    float4 _e = (E); \
    float f0_ = _e.x + b0, f1_ = _e.y + b1, f2_ = _e.z + b2, f3_ = _e.w + b3; \
    float n0_ = l2se3(A.A00 + f0_, A.A01 + f1_, A.A02 + f2_); \
    float n1_ = l2se3(A.A11 + f1_, A.A12 + f2_, A.A13 + f3_); \
    float n2_ = l2se2(A.A22 + f2_, A.A23 + f3_); \
    float n3_ = f3_; \
    float bm_ = fmaxf(fmaxf(n0_, n1_), fmaxf(n2_, n3_)); \
    b0 = n0_ - bm_; b1 = n1_ - bm_; b2 = n2_ - bm_; b3 = n3_ - bm_; \
} while (0)

#define GEMIT(AV, Q) do { \
    float g0_ = (AV).x + b0, g1_ = (AV).y + b1, g2_ = (AV).z + b2, g3_ = (AV).w + b3; \
    float gm_ = fmaxf(fmaxf(g0_, g1_), fmaxf(g2_, g3_)); \
    float q0_ = ex2(g0_ - gm_), q1_ = ex2(g1_ - gm_); \
    float q2_ = ex2(g2_ - gm_), q3_ = ex2(g3_ - gm_); \
    float inv_ = 1.f / (q0_ + q1_ + q2_ + q3_); \
    q0_ *= inv_; q1_ *= inv_; q2_ *= inv_; q3_ *= inv_; \
    vals[(Q)*5 + 0] = fmaf(q0_, wv[0][0], fmaf(q1_, wv[1][0], fmaf(q2_, wv[2][0], q3_ * wv[3][0]))); \
    vals[(Q)*5 + 1] = fmaf(q0_, wv[0][1], fmaf(q1_, wv[1][1], fmaf(q2_, wv[2][1], q3_ * wv[3][1]))); \
    vals[(Q)*5 + 2] = fmaf(q0_, wv[0][2], fmaf(q1_, wv[1][2], fmaf(q2_, wv[2][2], q3_ * wv[3][2]))); \
    vals[(Q)*5 + 3] = fmaf(q0_, wv[0][3], fmaf(q1_, wv[1][3], fmaf(q2_, wv[2][3], q3_ * wv[3][3]))); \
    vals[(Q)*5 + 4] = fmaf(q0_, wv[0][4], fmaf(q1_, wv[1][4], fmaf(q2_, wv[2][4], q3_ * wv[3][4]))); \
} while (0)

// le in LDS: row = t&15 (stride 257 float4), col = t>>4 (= chunk id) -> chunk readers contiguous
#define RDLE(T) sle[(((T) & 15) * 257) + ((T) >> 4)]

__global__ __launch_bounds__(768)
void fused_kernel(const float* __restrict__ x, const float* __restrict__ emit,
                  const float* __restrict__ trans, const float* __restrict__ initl,
                  const float* __restrict__ w, float* __restrict__ out) {
    __shared__ float4 sle[16 * 257];       // 65,792 B
    __shared__ float uniF[16448];          // 65,792 B: opsA/opsP (ph1-2) alias abuf/bbuf (ph3)
    __shared__ float vinL[CCH * 4];        // 4,096 B
    __shared__ float wbufL[CCH * 4];       // 4,096 B
    __shared__ float vin2[128 * 4];        // 2,048 B
    __shared__ float wbuf2[128 * 4];       // 2,048 B
    __shared__ float Bmat[SDIM][ADIM];     // 416 B

    float* opsA = uniF;                    // 512 units * 11 floats = 5632
    float* opsP = uniF + 5632;             // 256 pair-units * 11 = 2816
    float4* abuf = reinterpret_cast<float4*>(uniF);          // [k:0..7][cc] stride 257
    float4* bbuf = reinterpret_cast<float4*>(uniF) + 2056;   // [k:0..7][cc] stride 257

    const int tid = threadIdx.x;
    const int bidb = blockIdx.x;

    if (tid < SDIM) {
        float m = -1e30f;
        #pragma unroll
        for (int a = 0; a < ADIM; ++a) m = fmaxf(m, emit[tid * ADIM + a]);
        float tmp[ADIM];
        float z = 0.f;
        #pragma unroll
        for (int a = 0; a < ADIM; ++a) {
            float e = __expf(emit[tid * ADIM + a] - m);
            tmp[a] = e; z += e;
        }
        float inv = 1.f / z;
        #pragma unroll
        for (int a = 0; a < ADIM; ++a) Bmat[tid][a] = tmp[a] * inv;
    }
    TransA A = make_transA(trans);
    __syncthreads();

    // ---- phase 0: x[bidb] -> le in LDS; pair of rows per iter, accumulate-as-you-go ----
    for (int i = 0; i < 3; ++i) {
        int p = i * 768 + tid;                        // pair index
        if (p < 2048) {
            const float4* xp = reinterpret_cast<const float4*>(x) + ((size_t)bidb * 2048 + p) * 13;
            float z0 = 0.f, d00 = 0.f, d01 = 0.f, d02 = 0.f, d03 = 0.f;
            float z1 = 0.f, d10 = 0.f, d11 = 0.f, d12 = 0.f, d13 = 0.f;
            #pragma unroll
            for (int q2 = 0; q2 < 13; ++q2) {
                float4 u = xp[q2];
                #pragma unroll
                for (int j = 0; j < 4; ++j) {
                    const int e = q2 * 4 + j;         // compile-time
                    float val = (j == 0) ? u.x : (j == 1) ? u.y : (j == 2) ? u.z : u.w;
                    float ev = ex2(val * LOG2E);      // x ~ N(0,1): bounded
                    if (e < ADIM) {
                        z0 += ev;
                        d00 = fmaf(ev, Bmat[0][e], d00); d01 = fmaf(ev, Bmat[1][e], d01);
                        d02 = fmaf(ev, Bmat[2][e], d02); d03 = fmaf(ev, Bmat[3][e], d03);
                    } else {
                        z1 += ev;
                        d10 = fmaf(ev, Bmat[0][e - ADIM], d10); d11 = fmaf(ev, Bmat[1][e - ADIM], d11);
                        d12 = fmaf(ev, Bmat[2][e - ADIM], d12); d13 = fmaf(ev, Bmat[3][e - ADIM], d13);
                    }
                }
            }
            float iz0 = 1.f / z0, iz1 = 1.f / z1;
            float4 r0, r1;
            r0.x = lg2(fmaf(d00, iz0, 1e-16f)); r0.y = lg2(fmaf(d01, iz0, 1e-16f));
            r0.z = lg2(fmaf(d02, iz0, 1e-16f)); r0.w = lg2(fmaf(d03, iz0, 1e-16f));
            r1.x = lg2(fmaf(d10, iz1, 1e-16f)); r1.y = lg2(fmaf(d11, iz1, 1e-16f));
            r1.z = lg2(fmaf(d12, iz1, 1e-16f)); r1.w = lg2(fmaf(d13, iz1, 1e-16f));
            int t = p << 1;
            RDLE(t) = r0;
            RDLE(t + 1) = r1;
        }
    }
    __syncthreads();

    const int cc = tid & 255;
    const int t0 = cc * LCH;
    const bool isB = (tid & 511) >= 256;
    const bool worker = tid < 512;

    // ---- phase 1: per-(chunk,dir) operator, L=16 ----
    if (worker) {
        UT M;
        if (!isB) {
            float4 e0 = RDLE(t0);
            if (cc == 0) {
                M.m00 = e0.x; M.m11 = e0.y; M.m22 = e0.z; M.m33 = e0.w;
                M.m01 = NEGF; M.m02 = NEGF; M.m03 = NEGF; M.m12 = NEGF; M.m13 = NEGF; M.m23 = NEGF;
            } else {
                M.m00 = A.A00 + e0.x; M.m01 = A.A01 + e0.y; M.m02 = A.A02 + e0.z; M.m03 = NEGF;
                M.m11 = A.A11 + e0.y; M.m12 = A.A12 + e0.z; M.m13 = A.A13 + e0.w;
                M.m22 = A.A22 + e0.z; M.m23 = A.A23 + e0.w; M.m33 = e0.w;
            }
            #pragma unroll
            for (int k = 1; k < LCH; ++k) fstep(M, A, RDLE(t0 + k));
        } else {
            M.m00 = 0.f; M.m11 = 0.f; M.m22 = 0.f; M.m33 = 0.f;
            M.m01 = NEGF; M.m02 = NEGF; M.m03 = NEGF; M.m12 = NEGF; M.m13 = NEGF; M.m23 = NEGF;
            int nst = (cc == CCH - 1) ? (LCH - 1) : LCH;
            #pragma unroll
            for (int k = 0; k < LCH; ++k) {
                if (k < nst) fstep(M, A, RDLE(t0 + 1 + k));
            }
        }
        ut_renorm(M);
        ut_store(opsA + tid * 11, M);
    }
    __syncthreads();

    // ---- phase 2a: pair-compose 256 -> 128 ops per direction ----
    if (tid < 256) {
        int c2 = tid & 127;
        int base = (tid < 128) ? 0 : 256;            // fwd units 0..255, bwd 256..511
        UT P = ut_compose(ut_load(opsA + (base + 2 * c2) * 11),
                          ut_load(opsA + (base + 2 * c2 + 1) * 11));
        ut_renorm(P);
        ut_store(opsP + tid * 11, P);                // fwd pairs 0..127, bwd 128..255
    }
    __syncthreads();

    // ---- phase 2b: 8-lane serial scan over 128 pair-ops ----
    if (tid < 8) {
        int j = tid & 3;
        bool bwd = tid >= 4;
        float v;
        if (!bwd) {
            float i0 = initl[0], i1 = initl[1], i2 = initl[2], i3 = initl[3];
            float m = fmaxf(fmaxf(i0, i1), fmaxf(i2, i3));
            float lz = m + __logf(__expf(i0 - m) + __expf(i1 - m) + __expf(i2 - m) + __expf(i3 - m));
            float ij = (j == 0) ? i0 : (j == 1) ? i1 : (j == 2) ? i2 : i3;
            v = (ij - lz) * LOG2E;
        } else {
            v = 0.f;
        }
        int o0, o1, o2, o3;
        if (!bwd) {   // column j of UT
            o0 = (j == 0) ? 0 : (j == 1) ? 4 : (j == 2) ? 7 : 9;
            o1 = (j == 1) ? 1 : (j == 3) ? 8 : -1;
            o2 = (j == 2) ? 2 : (j == 3) ? 6 : -1;
            o3 = (j == 2) ? 5 : (j == 3) ? 3 : -1;
        } else {      // row j of UT
            o0 = (j == 0) ? 0 : (j == 1) ? 4 : (j == 2) ? 7 : 9;
            o1 = (j == 0) ? 1 : (j == 2) ? 8 : -1;
            o2 = (j == 0) ? 2 : (j == 1) ? 6 : -1;
            o3 = (j == 0) ? 3 : (j == 1) ? 5 : -1;
        }
        int dirbase = bwd ? 128 : 0;
        float* bp = bwd ? wbuf2 : vin2;
        for (int s = 0; s < 128; ++s) {
            int c2 = bwd ? (127 - s) : s;
            const float* pb = opsP + (dirbase + c2) * 11;
            float e0 = pb[o0];
            float e1 = (o1 >= 0) ? pb[o1] : NEGF;
            float e2 = (o2 >= 0) ? pb[o2] : NEGF;
            float e3 = (o3 >= 0) ? pb[o3] : NEGF;
            bp[c2 * 4 + j] = v;                      // boundary BEFORE applying pair-op
            float v1 = __shfl_xor(v, 1, 64);
            float v2 = __shfl_xor(v, 2, 64);
            float v3 = __shfl_xor(v1, 2, 64);
            float n = l2se4(v + e0, v1 + e1, v2 + e2, v3 + e3);
            float q = fmaxf(n, __shfl_xor(n, 1, 64));
            q = fmaxf(q, __shfl_xor(q, 2, 64));
            v = n - q;
        }
    }
    __syncthreads();

    // ---- phase 2c: odd/even boundary fill ----
    if (worker) {
        int h = cc >> 1;
        if (!isB) {
            float v0, v1, v2, v3;
            if ((cc & 1) == 0) {
                v0 = vin2[h * 4 + 0]; v1 = vin2[h * 4 + 1];
                v2 = vin2[h * 4 + 2]; v3 = vin2[h * 4 + 3];
            } else {
                float u0 = vin2[h * 4 + 0], u1 = vin2[h * 4 + 1];
                float u2 = vin2[h * 4 + 2], u3 = vin2[h * 4 + 3];
                UT M = ut_load(opsA + (cc - 1) * 11);       // fwd op of chunk cc-1
                v0 = u0 + M.m00;
                v1 = l2se2(u0 + M.m01, u1 + M.m11);
                v2 = l2se3(u0 + M.m02, u1 + M.m12, u2 + M.m22);
                v3 = l2se4(u0 + M.m03, u1 + M.m13, u2 + M.m23, u3 + M.m33);
                float mm = fmaxf(fmaxf(v0, v1), fmaxf(v2, v3));
                v0 -= mm; v1 -= mm; v2 -= mm; v3 -= mm;
            }
            vinL[cc * 4 + 0] = v0; vinL[cc * 4 + 1] = v1;
            vinL[cc * 4 + 2] = v2; vinL[cc * 4 + 3] = v3;
        } else {
            float v0, v1, v2, v3;
            if ((cc & 1) == 1) {
                v0 = wbuf2[h * 4 + 0]; v1 = wbuf2[h * 4 + 1];
                v2 = wbuf2[h * 4 + 2]; v3 = wbuf2[h * 4 + 3];
            } else {
                float u0 = wbuf2[h * 4 + 0], u1 = wbuf2[h * 4 + 1];
                float u2 = wbuf2[h * 4 + 2], u3 = wbuf2[h * 4 + 3];
                UT M = ut_load(opsA + (256 + cc + 1) * 11); // bwd op of chunk cc+1
                v0 = l2se4(M.m00 + u0, M.m01 + u1, M.m02 + u2, M.m03 + u3);
                v1 = l2se3(M.m11 + u1, M.m12 + u2, M.m13 + u3);
                v2 = l2se2(M.m22 + u2, M.m23 + u3);
                v3 = M.m33 + u3;
                float mm = fmaxf(fmaxf(v0, v1), fmaxf(v2, v3));
                v0 -= mm; v1 -= mm; v2 -= mm; v3 -= mm;
            }
            wbufL[cc * 4 + 0] = v0; wbufL[cc * 4 + 1] = v1;
            wbufL[cc * 4 + 2] = v2; wbufL[cc * 4 + 3] = v3;
        }
    }
    __syncthreads();

    // ---- phase 3: replay + gamma.w emit ----
    float wv[SDIM][5];
    #pragma unroll
    for (int s = 0; s < SDIM; ++s)
        #pragma unroll
        for (int o = 0; o < 5; ++o) wv[s][o] = w[s * 5 + o];

    float* opb = out + (size_t)bidb * TDIM * 5;
    float vals[20];
    float a0, a1, a2, a3, b0, b1, b2, b3;

    if (worker) {
        if (!isB) {
            a0 = vinL[cc * 4 + 0]; a1 = vinL[cc * 4 + 1];
            a2 = vinL[cc * 4 + 2]; a3 = vinL[cc * 4 + 3];
            if (cc == 0) {
                float4 e = RDLE(0);
                a0 += e.x; a1 += e.y; a2 += e.z; a3 += e.w;
                float mm = fmaxf(fmaxf(a0, a1), fmaxf(a2, a3));
                a0 -= mm; a1 -= mm; a2 -= mm; a3 -= mm;
            } else {
                ASTEP(RDLE(t0));
            }
            abuf[0 * 257 + cc] = make_float4(a0, a1, a2, a3);
            #pragma unroll
            for (int k = 1; k < 8; ++k) {
                ASTEP(RDLE(t0 + k));
                abuf[k * 257 + cc] = make_float4(a0, a1, a2, a3);
            }
        } else {
            b0 = wbufL[cc * 4 + 0]; b1 = wbufL[cc * 4 + 1];
            b2 = wbufL[cc * 4 + 2]; b3 = wbufL[cc * 4 + 3];
            bool lastc = (cc == CCH - 1);
            #pragma unroll
            for (int k = 15; k >= 8; --k) {
                if (!(lastc && k == 15)) BSTEP(RDLE(t0 + 1 + k));
                bbuf[(k - 8) * 257 + cc] = make_float4(b0, b1, b2, b3);
            }
        }
    }
    __syncthreads();

    if (worker) {
        if (!isB) {
            #pragma unroll
            for (int g = 2; g < 4; ++g) {
                #pragma unroll
                for (int q = 0; q < 4; ++q) {
                    int k = g * 4 + q;
                    ASTEP(RDLE(t0 + k));
                    float4 bv = bbuf[(k - 8) * 257 + cc];
                    b0 = bv.x; b1 = bv.y; b2 = bv.z; b3 = bv.w;
                    float4 av = make_float4(a0, a1, a2, a3);
                    GEMIT(av, q);
                }
                float4* vo = reinterpret_cast<float4*>(opb + (size_t)(t0 + g * 4) * 5);
                vo[0] = make_float4(vals[0],  vals[1],  vals[2],  vals[3]);
                vo[1] = make_float4(vals[4],  vals[5],  vals[6],  vals[7]);
                vo[2] = make_float4(vals[8],  vals[9],  vals[10], vals[11]);
                vo[3] = make_float4(vals[12], vals[13], vals[14], vals[15]);
                vo[4] = make_float4(vals[16], vals[17], vals[18], vals[19]);
            }
        } else {
            #pragma unroll
            for (int g = 1; g >= 0; --g) {
                #pragma unroll
                for (int q = 3; q >= 0; --q) {
                    int k = g * 4 + q;
                    BSTEP(RDLE(t0 + 1 + k));
                    float4 av = abuf[k * 257 + cc];
                    GEMIT(av, q);
                }
                float4* vo = reinterpret_cast<float4*>(opb + (size_t)(t0 + g * 4) * 5);
                vo[0] = make_float4(vals[0],  vals[1],  vals[2],  vals[3]);
                vo[1] = make_float4(vals[4],  vals[5],  vals[6],  vals[7]);
                vo[2] = make_float4(vals[8],  vals[9],  vals[10], vals[11]);
                vo[3] = make_float4(vals[12], vals[13], vals[14], vals[15]);
                vo[4] = make_float4(vals[16], vals[17], vals[18], vals[19]);
            }
        }
    }
}

extern "C" void kernel_launch(void* const* d_in, const int* in_sizes, int n_in,
                              void* d_out, int out_size, void* d_ws, size_t ws_size,
                              hipStream_t stream) {
    const float* x     = (const float*)d_in[0];
    const float* emit  = (const float*)d_in[1];
    const float* trans = (const float*)d_in[2];
    const float* initl = (const float*)d_in[3];
    const float* w     = (const float*)d_in[4];
    float* out = (float*)d_out;

    hipLaunchKernelGGL(fused_kernel, dim3(BDIM), dim3(768), 0, stream,
                       x, emit, trans, initl, w, out);
}

// Round 11
// 76.435 us; speedup vs baseline: 1.8781x; 1.8781x over previous
//
#include <hip/hip_runtime.h>
#include <hip/hip_fp16.h>

#define TDIM 4096
#define BDIM 256
#define ADIM 26
#define SDIM 4
#define LCH 16
#define CCH 256
#define NEGF -1e30f
#define LOG2E 1.44269504088896340736f

__device__ __forceinline__ float ex2(float x) { return __builtin_amdgcn_exp2f(x); }
__device__ __forceinline__ float lg2(float x) { return __builtin_amdgcn_logf(x); }

__device__ __forceinline__ float l2se2(float a, float b) {
    float mx = fmaxf(a, b), mn = fminf(a, b);
    return mx + lg2(1.f + ex2(mn - mx));
}
__device__ __forceinline__ float l2se3(float a, float b, float c) {
    float mx = fmaxf(fmaxf(a, b), c);
    float md = __builtin_amdgcn_fmed3f(a, b, c);
    float mn = fminf(fminf(a, b), c);
    return mx + lg2(1.f + ex2(md - mx) + ex2(mn - mx));
}
__device__ __forceinline__ float l2se4(float a, float b, float c, float d) {
    float h1 = fmaxf(a, b), l1 = fminf(a, b);
    float h2 = fmaxf(c, d), l2 = fminf(c, d);
    float mx = fmaxf(h1, h2), s2 = fminf(h1, h2);
    return mx + lg2(1.f + ex2(s2 - mx) + ex2(l1 - mx) + ex2(l2 - mx));
}

struct TransA { float A00, A01, A02, A11, A12, A13, A22, A23, A33; };

__device__ __forceinline__ TransA make_transA(const float* __restrict__ trans) {
    TransA A;
    {
        float l0 = trans[0], l1 = trans[1], l2 = trans[2];
        float m = fmaxf(fmaxf(l0, l1), l2);
        float lz = m + __logf(__expf(l0 - m) + __expf(l1 - m) + __expf(l2 - m));
        A.A00 = (l0 - lz) * LOG2E; A.A01 = (l1 - lz) * LOG2E; A.A02 = (l2 - lz) * LOG2E;
    }
    {
        float l1 = trans[5], l2 = trans[6], l3 = trans[7];
        float m = fmaxf(fmaxf(l1, l2), l3);
        float lz = m + __logf(__expf(l1 - m) + __expf(l2 - m) + __expf(l3 - m));
        A.A11 = (l1 - lz) * LOG2E; A.A12 = (l2 - lz) * LOG2E; A.A13 = (l3 - lz) * LOG2E;
    }
    {
        float l2 = trans[10], l3 = trans[11];
        float m = fmaxf(l2, l3);
        float lz = m + __logf(__expf(l2 - m) + __expf(l3 - m));
        A.A22 = (l2 - lz) * LOG2E; A.A23 = (l3 - lz) * LOG2E;
    }
    A.A33 = 0.f;
    return A;
}

struct UT { float m00, m01, m02, m03, m11, m12, m13, m22, m23, m33; };

__device__ __forceinline__ void fstep(UT& M, const TransA& A, float4 e) {
    float n00 = M.m00 + A.A00 + e.x;
    float n01 = l2se2(M.m00 + A.A01, M.m01 + A.A11) + e.y;
    float n02 = l2se3(M.m00 + A.A02, M.m01 + A.A12, M.m02 + A.A22) + e.z;
    float n03 = l2se3(M.m01 + A.A13, M.m02 + A.A23, M.m03) + e.w;
    float n11 = M.m11 + A.A11 + e.y;
    float n12 = l2se2(M.m11 + A.A12, M.m12 + A.A22) + e.z;
    float n13 = l2se3(M.m11 + A.A13, M.m12 + A.A23, M.m13) + e.w;
    float n22 = M.m22 + A.A22 + e.z;
    float n23 = l2se2(M.m22 + A.A23, M.m23) + e.w;
    float n33 = M.m33 + e.w;
    M.m00 = n00; M.m01 = n01; M.m02 = n02; M.m03 = n03;
    M.m11 = n11; M.m12 = n12; M.m13 = n13; M.m22 = n22; M.m23 = n23; M.m33 = n33;
}

// C = A (x) B (row-vec convention: v(x)C == (v(x)A)(x)B)
__device__ __forceinline__ UT ut_compose(const UT& A, const UT& B) {
    UT C;
    C.m00 = A.m00 + B.m00;
    C.m01 = l2se2(A.m00 + B.m01, A.m01 + B.m11);
    C.m02 = l2se3(A.m00 + B.m02, A.m01 + B.m12, A.m02 + B.m22);
    C.m03 = l2se4(A.m00 + B.m03, A.m01 + B.m13, A.m02 + B.m23, A.m03 + B.m33);
    C.m11 = A.m11 + B.m11;
    C.m12 = l2se2(A.m11 + B.m12, A.m12 + B.m22);
    C.m13 = l2se3(A.m11 + B.m13, A.m12 + B.m23, A.m13 + B.m33);
    C.m22 = A.m22 + B.m22;
    C.m23 = l2se2(A.m22 + B.m23, A.m23 + B.m33);
    C.m33 = A.m33 + B.m33;
    return C;
}

__device__ __forceinline__ void ut_renorm(UT& M) {
    float m1 = fmaxf(fmaxf(M.m00, M.m01), fmaxf(M.m02, M.m03));
    float m2 = fmaxf(fmaxf(M.m11, M.m12), fmaxf(M.m13, M.m22));
    float m3 = fmaxf(M.m23, M.m33);
    float mx = fmaxf(fmaxf(m1, m2), m3);
    M.m00 -= mx; M.m01 -= mx; M.m02 -= mx; M.m03 -= mx;
    M.m11 -= mx; M.m12 -= mx; M.m13 -= mx; M.m22 -= mx; M.m23 -= mx; M.m33 -= mx;
}

__device__ __forceinline__ void ut_store10(float* p, const UT& M) {
    p[0] = M.m00; p[1] = M.m01; p[2] = M.m02; p[3] = M.m03;
    p[4] = M.m11; p[5] = M.m12; p[6] = M.m13;
    p[7] = M.m22; p[8] = M.m23; p[9] = M.m33;
}
__device__ __forceinline__ UT ut_load10(const float* p) {
    UT M;
    M.m00 = p[0]; M.m01 = p[1]; M.m02 = p[2]; M.m03 = p[3];
    M.m11 = p[4]; M.m12 = p[5]; M.m13 = p[6];
    M.m22 = p[7]; M.m23 = p[8]; M.m33 = p[9];
    return M;
}

#define ASTEP(E) do { \
    float4 _e = (E); \
    float n0_ = a0 + A.A00; \
    float n1_ = l2se2(a0 + A.A01, a1 + A.A11); \
    float n2_ = l2se3(a0 + A.A02, a1 + A.A12, a2 + A.A22); \
    float n3_ = l2se3(a1 + A.A13, a2 + A.A23, a3); \
    a0 = n0_ + _e.x; a1 = n1_ + _e.y; a2 = n2_ + _e.z; a3 = n3_ + _e.w; \
    float mm_ = fmaxf(fmaxf(a0, a1), fmaxf(a2, a3)); \
    a0 -= mm_; a1 -= mm_; a2 -= mm_; a3 -= mm_; \
} while (0)

#define BSTEP(E) do { \
    float4 _e = (E); \
    float f0_ = _e.x + b0, f1_ = _e.y + b1, f2_ = _e.z + b2, f3_ = _e.w + b3; \
    float n0_ = l2se3(A.A00 + f0_, A.A01 + f1_, A.A02 + f2_); \
    float n1_ = l2se3(A.A11 + f1_, A.A12 + f2_, A.A13 + f3_); \
    float n2_ = l2se2(A.A22 + f2_, A.A23 + f3_); \
    float n3_ = f3_; \
    float bm_ = fmaxf(fmaxf(n0_, n1_), fmaxf(n2_, n3_)); \
    b0 = n0_ - bm_; b1 = n1_ - bm_; b2 = n2_ - bm_; b3 = n3_ - bm_; \
} while (0)

#define GEMIT(AV, Q) do { \
    float g0_ = (AV).x + b0, g1_ = (AV).y + b1, g2_ = (AV).z + b2, g3_ = (AV).w + b3; \
    float gm_ = fmaxf(fmaxf(g0_, g1_), fmaxf(g2_, g3_)); \
    float q0_ = ex2(g0_ - gm_), q1_ = ex2(g1_ - gm_); \
    float q2_ = ex2(g2_ - gm_), q3_ = ex2(g3_ - gm_); \
    float inv_ = 1.f / (q0_ + q1_ + q2_ + q3_); \
    q0_ *= inv_; q1_ *= inv_; q2_ *= inv_; q3_ *= inv_; \
    vals[(Q)*5 + 0] = fmaf(q0_, wv[0][0], fmaf(q1_, wv[1][0], fmaf(q2_, wv[2][0], q3_ * wv[3][0]))); \
    vals[(Q)*5 + 1] = fmaf(q0_, wv[0][1], fmaf(q1_, wv[1][1], fmaf(q2_, wv[2][1], q3_ * wv[3][1]))); \
    vals[(Q)*5 + 2] = fmaf(q0_, wv[0][2], fmaf(q1_, wv[1][2], fmaf(q2_, wv[2][2], q3_ * wv[3][2]))); \
    vals[(Q)*5 + 3] = fmaf(q0_, wv[0][3], fmaf(q1_, wv[1][3], fmaf(q2_, wv[2][3], q3_ * wv[3][3]))); \
    vals[(Q)*5 + 4] = fmaf(q0_, wv[0][4], fmaf(q1_, wv[1][4], fmaf(q2_, wv[2][4], q3_ * wv[3][4]))); \
} while (0)

// fp16 le tile: row = t&15 (stride 257), col = t>>4 = chunk id
struct H4 { __half2 lo, hi; };

__global__ __launch_bounds__(256, 2)
void fused_kernel(const float* __restrict__ x, const float* __restrict__ emit,
                  const float* __restrict__ trans, const float* __restrict__ initl,
                  const float* __restrict__ w, float* __restrict__ out) {
    __shared__ H4 sle[16 * 257];           // 32,896 B
    __shared__ float opsF[CCH * 10];       // 10,240 B
    __shared__ float opsB[CCH * 10];       // 10,240 B
    __shared__ float opsP[CCH * 10];       // 10,240 B
    __shared__ float vin2[128 * 4];        // 2,048 B
    __shared__ float wbuf2[128 * 4];       // 2,048 B
    __shared__ float Bmat[SDIM][ADIM];     // 416 B   (total ~68 KB -> 2 blocks/CU)

    const int tid = threadIdx.x;
    const int bidb = blockIdx.x;

#define RDLE(T) ({ H4 h_ = sle[(((T) & 15) * 257) + ((T) >> 4)]; \
                   float2 lo_ = __half22float2(h_.lo); float2 hi_ = __half22float2(h_.hi); \
                   make_float4(lo_.x, lo_.y, hi_.x, hi_.y); })

    if (tid < SDIM) {
        float m = -1e30f;
        #pragma unroll
        for (int a = 0; a < ADIM; ++a) m = fmaxf(m, emit[tid * ADIM + a]);
        float tmp[ADIM];
        float z = 0.f;
        #pragma unroll
        for (int a = 0; a < ADIM; ++a) {
            float e = __expf(emit[tid * ADIM + a] - m);
            tmp[a] = e; z += e;
        }
        float inv = 1.f / z;
        #pragma unroll
        for (int a = 0; a < ADIM; ++a) Bmat[tid][a] = tmp[a] * inv;
    }
    TransA A = make_transA(trans);
    __syncthreads();

    // ---- phase 0: x[bidb] -> fp16 le in LDS (2 rows/thread-iter, aligned float4 loads) ----
    #pragma unroll 2
    for (int i = 0; i < 8; ++i) {
        int p = i * 256 + tid;                       // pair index 0..2047
        const float4* xp = reinterpret_cast<const float4*>(x) + ((size_t)bidb * 2048 + p) * 13;
        float v[52];
        #pragma unroll
        for (int q2 = 0; q2 < 13; ++q2) {
            float4 u = xp[q2];
            v[q2 * 4 + 0] = u.x; v[q2 * 4 + 1] = u.y;
            v[q2 * 4 + 2] = u.z; v[q2 * 4 + 3] = u.w;
        }
        float4 r0, r1;
        {
            float z = 0.f, d0 = 0.f, d1 = 0.f, d2 = 0.f, d3 = 0.f;
            #pragma unroll
            for (int a = 0; a < ADIM; ++a) {
                float e = ex2(v[a] * LOG2E);         // x ~ N(0,1): bounded
                z += e;
                d0 = fmaf(e, Bmat[0][a], d0); d1 = fmaf(e, Bmat[1][a], d1);
                d2 = fmaf(e, Bmat[2][a], d2); d3 = fmaf(e, Bmat[3][a], d3);
            }
            float iz = 1.f / z;
            r0.x = lg2(fmaf(d0, iz, 1e-16f)); r0.y = lg2(fmaf(d1, iz, 1e-16f));
            r0.z = lg2(fmaf(d2, iz, 1e-16f)); r0.w = lg2(fmaf(d3, iz, 1e-16f));
        }
        {
            float z = 0.f, d0 = 0.f, d1 = 0.f, d2 = 0.f, d3 = 0.f;
            #pragma unroll
            for (int a = 0; a < ADIM; ++a) {
                float e = ex2(v[26 + a] * LOG2E);
                z += e;
                d0 = fmaf(e, Bmat[0][a], d0); d1 = fmaf(e, Bmat[1][a], d1);
                d2 = fmaf(e, Bmat[2][a], d2); d3 = fmaf(e, Bmat[3][a], d3);
            }
            float iz = 1.f / z;
            r1.x = lg2(fmaf(d0, iz, 1e-16f)); r1.y = lg2(fmaf(d1, iz, 1e-16f));
            r1.z = lg2(fmaf(d2, iz, 1e-16f)); r1.w = lg2(fmaf(d3, iz, 1e-16f));
        }
        int t = p << 1;
        H4 h0, h1;
        h0.lo = __floats2half2_rn(r0.x, r0.y); h0.hi = __floats2half2_rn(r0.z, r0.w);
        h1.lo = __floats2half2_rn(r1.x, r1.y); h1.hi = __floats2half2_rn(r1.z, r1.w);
        sle[((t & 15) * 257) + (t >> 4)] = h0;
        sle[(((t + 1) & 15) * 257) + ((t + 1) >> 4)] = h1;
    }
    __syncthreads();

    const int cc = tid;
    const int t0 = cc * LCH;

    // ---- phase 1: fwd M_cc and bwd N_cc, interleaved (ILP-2) ----
    {
        UT Mf, Mb;
        float4 e0 = RDLE(t0);
        if (cc == 0) {
            Mf.m00 = e0.x; Mf.m11 = e0.y; Mf.m22 = e0.z; Mf.m33 = e0.w;
            Mf.m01 = NEGF; Mf.m02 = NEGF; Mf.m03 = NEGF; Mf.m12 = NEGF; Mf.m13 = NEGF; Mf.m23 = NEGF;
        } else {
            Mf.m00 = A.A00 + e0.x; Mf.m01 = A.A01 + e0.y; Mf.m02 = A.A02 + e0.z; Mf.m03 = NEGF;
            Mf.m11 = A.A11 + e0.y; Mf.m12 = A.A12 + e0.z; Mf.m13 = A.A13 + e0.w;
            Mf.m22 = A.A22 + e0.z; Mf.m23 = A.A23 + e0.w; Mf.m33 = e0.w;
        }
        Mb.m00 = 0.f; Mb.m11 = 0.f; Mb.m22 = 0.f; Mb.m33 = 0.f;
        Mb.m01 = NEGF; Mb.m02 = NEGF; Mb.m03 = NEGF; Mb.m12 = NEGF; Mb.m13 = NEGF; Mb.m23 = NEGF;
        #pragma unroll
        for (int k = 1; k <= 16; ++k) {
            if (k <= 15) {
                float4 e = RDLE(t0 + k);
                fstep(Mf, A, e);
                fstep(Mb, A, e);              // bwd atom at t0+k (k=1..15), shared read
            } else if (cc < CCH - 1) {
                fstep(Mb, A, RDLE(t0 + 16));  // bwd atom k=16 (skip for last chunk)
            }
        }
        ut_renorm(Mf); ut_renorm(Mb);
        ut_store10(opsF + cc * 10, Mf);
        ut_store10(opsB + cc * 10, Mb);
    }
    __syncthreads();

    // ---- phase 2a: pair-compose 256 -> 128 per direction ----
    {
        int h = tid & 127;
        const float* src = (tid < 128) ? opsF : opsB;
        UT P = ut_compose(ut_load10(src + (2 * h) * 10), ut_load10(src + (2 * h + 1) * 10));
        ut_renorm(P);
        ut_store10(opsP + tid * 10, P);       // fwd pairs 0..127, bwd pairs 128..255
    }
    __syncthreads();

    // ---- phase 2b: 8-lane serial scan over 128 pair-ops ----
    if (tid < 8) {
        int j = tid & 3;
        bool bwd = tid >= 4;
        float v;
        if (!bwd) {
            float i0 = initl[0], i1 = initl[1], i2 = initl[2], i3 = initl[3];
            float m = fmaxf(fmaxf(i0, i1), fmaxf(i2, i3));
            float lz = m + __logf(__expf(i0 - m) + __expf(i1 - m) + __expf(i2 - m) + __expf(i3 - m));
            float ij = (j == 0) ? i0 : (j == 1) ? i1 : (j == 2) ? i2 : i3;
            v = (ij - lz) * LOG2E;
        } else {
            v = 0.f;
        }
        int o0, o1, o2, o3;
        if (!bwd) {   // column j of UT
            o0 = (j == 0) ? 0 : (j == 1) ? 4 : (j == 2) ? 7 : 9;
            o1 = (j == 1) ? 1 : (j == 3) ? 8 : -1;
            o2 = (j == 2) ? 2 : (j == 3) ? 6 : -1;
            o3 = (j == 2) ? 5 : (j == 3) ? 3 : -1;
        } else {      // row j of UT
            o0 = (j == 0) ? 0 : (j == 1) ? 4 : (j == 2) ? 7 : 9;
            o1 = (j == 0) ? 1 : (j == 2) ? 8 : -1;
            o2 = (j == 0) ? 2 : (j == 1) ? 6 : -1;
            o3 = (j == 0) ? 3 : (j == 1) ? 5 : -1;
        }
        int dirbase = bwd ? 128 : 0;
        float* bp = bwd ? wbuf2 : vin2;
        for (int s = 0; s < 128; ++s) {
            int c2 = bwd ? (127 - s) : s;
            const float* pb = opsP + (dirbase + c2) * 10;
            float e0 = pb[o0];
            float e1 = (o1 >= 0) ? pb[o1] : NEGF;
            float e2 = (o2 >= 0) ? pb[o2] : NEGF;
            float e3 = (o3 >= 0) ? pb[o3] : NEGF;
            bp[c2 * 4 + j] = v;                      // boundary BEFORE applying pair-op
            float v1 = __shfl_xor(v, 1, 64);
            float v2 = __shfl_xor(v, 2, 64);
            float v3 = __shfl_xor(v1, 2, 64);
            float n = l2se4(v + e0, v1 + e1, v2 + e2, v3 + e3);
            float q = fmaxf(n, __shfl_xor(n, 1, 64));
            q = fmaxf(q, __shfl_xor(q, 2, 64));
            v = n - q;
        }
    }
    __syncthreads();

    // ---- phase 2c: per-chunk boundaries, in registers ----
    float fa0, fa1, fa2, fa3;     // alpha boundary entering chunk cc
    float fb0, fb1, fb2, fb3;     // beta boundary at end of chunk cc
    {
        int h = cc >> 1;
        float u0 = vin2[h * 4 + 0], u1 = vin2[h * 4 + 1];
        float u2 = vin2[h * 4 + 2], u3 = vin2[h * 4 + 3];
        if (cc & 1) {
            UT M = ut_load10(opsF + (cc - 1) * 10);
            fa0 = u0 + M.m00;
            fa1 = l2se2(u0 + M.m01, u1 + M.m11);
            fa2 = l2se3(u0 + M.m02, u1 + M.m12, u2 + M.m22);
            fa3 = l2se4(u0 + M.m03, u1 + M.m13, u2 + M.m23, u3 + M.m33);
            float mm = fmaxf(fmaxf(fa0, fa1), fmaxf(fa2, fa3));
            fa0 -= mm; fa1 -= mm; fa2 -= mm; fa3 -= mm;
        } else {
            fa0 = u0; fa1 = u1; fa2 = u2; fa3 = u3;
        }
        float z0 = wbuf2[h * 4 + 0], z1 = wbuf2[h * 4 + 1];
        float z2 = wbuf2[h * 4 + 2], z3 = wbuf2[h * 4 + 3];
        if (cc & 1) {
            fb0 = z0; fb1 = z1; fb2 = z2; fb3 = z3;
        } else {
            UT M = ut_load10(opsB + (cc + 1) * 10);
            fb0 = l2se4(M.m00 + z0, M.m01 + z1, M.m02 + z2, M.m03 + z3);
            fb1 = l2se3(M.m11 + z1, M.m12 + z2, M.m13 + z3);
            fb2 = l2se2(M.m22 + z2, M.m23 + z3);
            fb3 = M.m33 + z3;
            float mm = fmaxf(fmaxf(fb0, fb1), fmaxf(fb2, fb3));
            fb0 -= mm; fb1 -= mm; fb2 -= mm; fb3 -= mm;
        }
    }

    // ---- phase 3: beta into registers, then alpha replay + emit ----
    float wv[SDIM][5];
    #pragma unroll
    for (int s = 0; s < SDIM; ++s)
        #pragma unroll
        for (int o = 0; o < 5; ++o) wv[s][o] = w[s * 5 + o];

    float4 betar[16];
    {
        float b0 = fb0, b1 = fb1, b2 = fb2, b3 = fb3;
        #pragma unroll
        for (int k = 15; k >= 0; --k) {
            if (!(cc == CCH - 1 && k == 15)) BSTEP(RDLE(t0 + 1 + k));
            betar[k] = make_float4(b0, b1, b2, b3);
        }
    }

    float* opb = out + (size_t)bidb * TDIM * 5;
    float vals[20];
    float a0 = fa0, a1 = fa1, a2 = fa2, a3 = fa3;

    #pragma unroll
    for (int g = 0; g < 4; ++g) {
        #pragma unroll
        for (int q = 0; q < 4; ++q) {
            int k = g * 4 + q;
            if (cc == 0 && k == 0) {
                float4 e = RDLE(0);
                a0 += e.x; a1 += e.y; a2 += e.z; a3 += e.w;
                float mm = fmaxf(fmaxf(a0, a1), fmaxf(a2, a3));
                a0 -= mm; a1 -= mm; a2 -= mm; a3 -= mm;
            } else {
                ASTEP(RDLE(t0 + k));
            }
            float b0 = betar[k].x, b1 = betar[k].y, b2 = betar[k].z, b3 = betar[k].w;
            float4 av = make_float4(a0, a1, a2, a3);
            GEMIT(av, q);
        }
        float4* vo = reinterpret_cast<float4*>(opb + (size_t)(t0 + g * 4) * 5);
        vo[0] = make_float4(vals[0],  vals[1],  vals[2],  vals[3]);
        vo[1] = make_float4(vals[4],  vals[5],  vals[6],  vals[7]);
        vo[2] = make_float4(vals[8],  vals[9],  vals[10], vals[11]);
        vo[3] = make_float4(vals[12], vals[13], vals[14], vals[15]);
        vo[4] = make_float4(vals[16], vals[17], vals[18], vals[19]);
    }
}

extern "C" void kernel_launch(void* const* d_in, const int* in_sizes, int n_in,
                              void* d_out, int out_size, void* d_ws, size_t ws_size,
                              hipStream_t stream) {
    const float* x     = (const float*)d_in[0];
    const float* emit  = (const float*)d_in[1];
    const float* trans = (const float*)d_in[2];
    const float* initl = (const float*)d_in[3];
    const float* w     = (const float*)d_in[4];
    float* out = (float*)d_out;

    hipLaunchKernelGGL(fused_kernel, dim3(BDIM), dim3(256), 0, stream,
                       x, emit, trans, initl, w, out);
}

// Round 12
// 64.005 us; speedup vs baseline: 2.2429x; 1.1942x over previous
//
#include <hip/hip_runtime.h>

#define TDIM 4096
#define BDIM 256
#define ADIM 26
#define SDIM 4
#define NEGF -1e30f
#define LOG2E 1.44269504088896340736f

__device__ __forceinline__ float ex2(float x) { return __builtin_amdgcn_exp2f(x); }
__device__ __forceinline__ float lg2(float x) { return __builtin_amdgcn_logf(x); }

__device__ __forceinline__ float l2se2(float a, float b) {
    float mx = fmaxf(a, b), mn = fminf(a, b);
    return mx + lg2(1.f + ex2(mn - mx));
}
__device__ __forceinline__ float l2se3(float a, float b, float c) {
    float mx = fmaxf(fmaxf(a, b), c);
    float md = __builtin_amdgcn_fmed3f(a, b, c);
    float mn = fminf(fminf(a, b), c);
    return mx + lg2(1.f + ex2(md - mx) + ex2(mn - mx));
}
__device__ __forceinline__ float l2se4(float a, float b, float c, float d) {
    float h1 = fmaxf(a, b), l1 = fminf(a, b);
    float h2 = fmaxf(c, d), l2 = fminf(c, d);
    float mx = fmaxf(h1, h2), s2 = fminf(h1, h2);
    return mx + lg2(1.f + ex2(s2 - mx) + ex2(l1 - mx) + ex2(l2 - mx));
}

struct TransA { float A00, A01, A02, A11, A12, A13, A22, A23, A33; };

__device__ __forceinline__ TransA make_transA(const float* __restrict__ trans) {
    TransA A;
    {
        float l0 = trans[0], l1 = trans[1], l2 = trans[2];
        float m = fmaxf(fmaxf(l0, l1), l2);
        float lz = m + __logf(__expf(l0 - m) + __expf(l1 - m) + __expf(l2 - m));
        A.A00 = (l0 - lz) * LOG2E; A.A01 = (l1 - lz) * LOG2E; A.A02 = (l2 - lz) * LOG2E;
    }
    {
        float l1 = trans[5], l2 = trans[6], l3 = trans[7];
        float m = fmaxf(fmaxf(l1, l2), l3);
        float lz = m + __logf(__expf(l1 - m) + __expf(l2 - m) + __expf(l3 - m));
        A.A11 = (l1 - lz) * LOG2E; A.A12 = (l2 - lz) * LOG2E; A.A13 = (l3 - lz) * LOG2E;
    }
    {
        float l2 = trans[10], l3 = trans[11];
        float m = fmaxf(l2, l3);
        float lz = m + __logf(__expf(l2 - m) + __expf(l3 - m));
        A.A22 = (l2 - lz) * LOG2E; A.A23 = (l3 - lz) * LOG2E;
    }
    A.A33 = 0.f;
    return A;
}

struct UT { float m00, m01, m02, m03, m11, m12, m13, m22, m23, m33; };

__device__ __forceinline__ void fstep(UT& M, const TransA& A, float4 e) {
    float n00 = M.m00 + A.A00 + e.x;
    float n01 = l2se2(M.m00 + A.A01, M.m01 + A.A11) + e.y;
    float n02 = l2se3(M.m00 + A.A02, M.m01 + A.A12, M.m02 + A.A22) + e.z;
    float n03 = l2se3(M.m01 + A.A13, M.m02 + A.A23, M.m03) + e.w;
    float n11 = M.m11 + A.A11 + e.y;
    float n12 = l2se2(M.m11 + A.A12, M.m12 + A.A22) + e.z;
    float n13 = l2se3(M.m11 + A.A13, M.m12 + A.A23, M.m13) + e.w;
    float n22 = M.m22 + A.A22 + e.z;
    float n23 = l2se2(M.m22 + A.A23, M.m23) + e.w;
    float n33 = M.m33 + e.w;
    M.m00 = n00; M.m01 = n01; M.m02 = n02; M.m03 = n03;
    M.m11 = n11; M.m12 = n12; M.m13 = n13; M.m22 = n22; M.m23 = n23; M.m33 = n33;
}

// C = A(x)B = A.B matrix product in log semiring (row-vec: v(x)C == (v(x)A)(x)B; col: C(x)u == A(x)(B(x)u))
__device__ __forceinline__ UT ut_compose(const UT& A, const UT& B) {
    UT C;
    C.m00 = A.m00 + B.m00;
    C.m01 = l2se2(A.m00 + B.m01, A.m01 + B.m11);
    C.m02 = l2se3(A.m00 + B.m02, A.m01 + B.m12, A.m02 + B.m22);
    C.m03 = l2se4(A.m00 + B.m03, A.m01 + B.m13, A.m02 + B.m23, A.m03 + B.m33);
    C.m11 = A.m11 + B.m11;
    C.m12 = l2se2(A.m11 + B.m12, A.m12 + B.m22);
    C.m13 = l2se3(A.m11 + B.m13, A.m12 + B.m23, A.m13 + B.m33);
    C.m22 = A.m22 + B.m22;
    C.m23 = l2se2(A.m22 + B.m23, A.m23 + B.m33);
    C.m33 = A.m33 + B.m33;
    return C;
}

__device__ __forceinline__ void ut_renorm(UT& M) {
    float m1 = fmaxf(fmaxf(M.m00, M.m01), fmaxf(M.m02, M.m03));
    float m2 = fmaxf(fmaxf(M.m11, M.m12), fmaxf(M.m13, M.m22));
    float m3 = fmaxf(M.m23, M.m33);
    float mx = fmaxf(fmaxf(m1, m2), m3);
    M.m00 -= mx; M.m01 -= mx; M.m02 -= mx; M.m03 -= mx;
    M.m11 -= mx; M.m12 -= mx; M.m13 -= mx; M.m22 -= mx; M.m23 -= mx; M.m33 -= mx;
}

__device__ __forceinline__ void ut_store11(float* p, const UT& M) {
    p[0] = M.m00; p[1] = M.m01; p[2] = M.m02; p[3] = M.m03;
    p[4] = M.m11; p[5] = M.m12; p[6] = M.m13;
    p[7] = M.m22; p[8] = M.m23; p[9] = M.m33;
}
__device__ __forceinline__ UT ut_load11(const float* p) {
    UT M;
    M.m00 = p[0]; M.m01 = p[1]; M.m02 = p[2]; M.m03 = p[3];
    M.m11 = p[4]; M.m12 = p[5]; M.m13 = p[6];
    M.m22 = p[7]; M.m23 = p[8]; M.m33 = p[9];
    return M;
}

// v' = v (x) M  (row-vec through op), with renorm
__device__ __forceinline__ void vecmat(float& v0, float& v1, float& v2, float& v3,
                                       const float* m) {
    float n0 = v0 + m[0];
    float n1 = l2se2(v0 + m[1], v1 + m[4]);
    float n2 = l2se3(v0 + m[2], v1 + m[5], v2 + m[7]);
    float n3 = l2se4(v0 + m[3], v1 + m[6], v2 + m[8], v3 + m[9]);
    float mm = fmaxf(fmaxf(n0, n1), fmaxf(n2, n3));
    v0 = n0 - mm; v1 = n1 - mm; v2 = n2 - mm; v3 = n3 - mm;
}
// u' = M (x) u  (op through col-vec), with renorm
__device__ __forceinline__ void matvec(const float* m,
                                       float& u0, float& u1, float& u2, float& u3) {
    float n0 = l2se4(m[0] + u0, m[1] + u1, m[2] + u2, m[3] + u3);
    float n1 = l2se3(m[4] + u1, m[5] + u2, m[6] + u3);
    float n2 = l2se2(m[7] + u2, m[8] + u3);
    float n3 = m[9] + u3;
    float mm = fmaxf(fmaxf(n0, n1), fmaxf(n2, n3));
    u0 = n0 - mm; u1 = n1 - mm; u2 = n2 - mm; u3 = n3 - mm;
}

#define ASTEP(E) do { \
    float4 _e = (E); \
    float n0_ = a0 + A.A00; \
    float n1_ = l2se2(a0 + A.A01, a1 + A.A11); \
    float n2_ = l2se3(a0 + A.A02, a1 + A.A12, a2 + A.A22); \
    float n3_ = l2se3(a1 + A.A13, a2 + A.A23, a3); \
    a0 = n0_ + _e.x; a1 = n1_ + _e.y; a2 = n2_ + _e.z; a3 = n3_ + _e.w; \
    float mm_ = fmaxf(fmaxf(a0, a1), fmaxf(a2, a3)); \
    a0 -= mm_; a1 -= mm_; a2 -= mm_; a3 -= mm_; \
} while (0)

#define BSTEP(E) do { \
    float4 _e = (E); \
    float f0_ = _e.x + b0, f1_ = _e.y + b1, f2_ = _e.z + b2, f3_ = _e.w + b3; \
    float n0_ = l2se3(A.A00 + f0_, A.A01 + f1_, A.A02 + f2_); \
    float n1_ = l2se3(A.A11 + f1_, A.A12 + f2_, A.A13 + f3_); \
    float n2_ = l2se2(A.A22 + f2_, A.A23 + f3_); \
    float n3_ = f3_; \
    float bm_ = fmaxf(fmaxf(n0_, n1_), fmaxf(n2_, n3_)); \
    b0 = n0_ - bm_; b1 = n1_ - bm_; b2 = n2_ - bm_; b3 = n3_ - bm_; \
} while (0)

#define GEMIT(AV, Q) do { \
    float g0_ = (AV).x + b0, g1_ = (AV).y + b1, g2_ = (AV).z + b2, g3_ = (AV).w + b3; \
    float gm_ = fmaxf(fmaxf(g0_, g1_), fmaxf(g2_, g3_)); \
    float q0_ = ex2(g0_ - gm_), q1_ = ex2(g1_ - gm_); \
    float q2_ = ex2(g2_ - gm_), q3_ = ex2(g3_ - gm_); \
    float inv_ = 1.f / (q0_ + q1_ + q2_ + q3_); \
    q0_ *= inv_; q1_ *= inv_; q2_ *= inv_; q3_ *= inv_; \
    vals[(Q)*5 + 0] = fmaf(q0_, wv[0][0], fmaf(q1_, wv[1][0], fmaf(q2_, wv[2][0], q3_ * wv[3][0]))); \
    vals[(Q)*5 + 1] = fmaf(q0_, wv[0][1], fmaf(q1_, wv[1][1], fmaf(q2_, wv[2][1], q3_ * wv[3][1]))); \
    vals[(Q)*5 + 2] = fmaf(q0_, wv[0][2], fmaf(q1_, wv[1][2], fmaf(q2_, wv[2][2], q3_ * wv[3][2]))); \
    vals[(Q)*5 + 3] = fmaf(q0_, wv[0][3], fmaf(q1_, wv[1][3], fmaf(q2_, wv[2][3], q3_ * wv[3][3]))); \
    vals[(Q)*5 + 4] = fmaf(q0_, wv[0][4], fmaf(q1_, wv[1][4], fmaf(q2_, wv[2][4], q3_ * wv[3][4]))); \
} while (0)

// le in LDS: row = t&31 (stride 129 float4), col = t>>5 = chunk id (C=128, L=32)
#define RDLE(T) sle[(((T) & 31) * 129) + ((T) >> 5)]

// LDS float-offsets inside uni for the op tree (stride 11 per op slot)
#define L0F 0
#define L0B 1408
#define L1F 2816
#define L1B 3520
#define L2F 4224
#define L2B 4576
#define SF  4928
#define SB  5056

__global__ __launch_bounds__(256, 1)
void fused_kernel(const float* __restrict__ x, const float* __restrict__ emit,
                  const float* __restrict__ trans, const float* __restrict__ initl,
                  const float* __restrict__ w, float* __restrict__ out) {
    __shared__ float4 sle[32 * 129];    // 66,048 B
    __shared__ float4 uni[4352];        // 69,632 B: op tree (ph1/2) aliased by alpha/beta (ph3)
    __shared__ float Bmat[SDIM][ADIM];  // 416 B

    float* U = reinterpret_cast<float*>(uni);
    float4* abuf = uni;                 // [c*17 + k], c<128, k<16  (phase 3)
    float4* bbuf = uni + 2176;

    const int tid = threadIdx.x;
    const int bidb = blockIdx.x;

    // ---- emission distributions ----
    if (tid < SDIM) {
        float m = -1e30f;
        #pragma unroll
        for (int a = 0; a < ADIM; ++a) m = fmaxf(m, emit[tid * ADIM + a]);
        float tmp[ADIM];
        float z = 0.f;
        #pragma unroll
        for (int a = 0; a < ADIM; ++a) {
            float e = __expf(emit[tid * ADIM + a] - m);
            tmp[a] = e; z += e;
        }
        float inv = 1.f / z;
        #pragma unroll
        for (int a = 0; a < ADIM; ++a) Bmat[tid][a] = tmp[a] * inv;
    }
    TransA A = make_transA(trans);
    __syncthreads();

    // ---- phase 0: x[bidb] -> le in LDS; register double-buffer prefetch ----
    // le_j = log2(sum_a e^{x_a} B_ja)  -- unnormalized (z dropped; gamma invariant to per-t shifts)
    {
        const float4* xbase = reinterpret_cast<const float4*>(x) + (size_t)bidb * 2048 * 13;

#define LOADP(B, I) do { \
    const float4* xp_ = xbase + ((size_t)(I) * 256 + tid) * 13; \
    _Pragma("unroll") \
    for (int q_ = 0; q_ < 13; ++q_) B[q_] = xp_[q_]; \
} while (0)

#define COMPUTE(B, I) do { \
    float d00 = 0.f, d01 = 0.f, d02 = 0.f, d03 = 0.f; \
    float d10 = 0.f, d11 = 0.f, d12 = 0.f, d13 = 0.f; \
    _Pragma("unroll") \
    for (int q_ = 0; q_ < 13; ++q_) { \
        float4 u_ = B[q_]; \
        _Pragma("unroll") \
        for (int j_ = 0; j_ < 4; ++j_) { \
            const int e_ = q_ * 4 + j_; \
            float val_ = (j_ == 0) ? u_.x : (j_ == 1) ? u_.y : (j_ == 2) ? u_.z : u_.w; \
            float ev_ = ex2(val_ * LOG2E); \
            if (e_ < ADIM) { \
                d00 = fmaf(ev_, Bmat[0][e_], d00); d01 = fmaf(ev_, Bmat[1][e_], d01); \
                d02 = fmaf(ev_, Bmat[2][e_], d02); d03 = fmaf(ev_, Bmat[3][e_], d03); \
            } else { \
                const int a_ = e_ - ADIM; \
                d10 = fmaf(ev_, Bmat[0][a_], d10); d11 = fmaf(ev_, Bmat[1][a_], d11); \
                d12 = fmaf(ev_, Bmat[2][a_], d12); d13 = fmaf(ev_, Bmat[3][a_], d13); \
            } \
        } \
    } \
    float4 r0_, r1_; \
    r0_.x = lg2(d00); r0_.y = lg2(d01); r0_.z = lg2(d02); r0_.w = lg2(d03); \
    r1_.x = lg2(d10); r1_.y = lg2(d11); r1_.z = lg2(d12); r1_.w = lg2(d13); \
    int t_ = (((I) * 256 + tid)) << 1; \
    RDLE(t_) = r0_; \
    RDLE(t_ + 1) = r1_; \
} while (0)

        float4 bufA[13], bufB[13];
        LOADP(bufA, 0);
        #pragma unroll
        for (int i = 0; i < 4; ++i) {
            LOADP(bufB, 2 * i + 1);
            COMPUTE(bufA, 2 * i);
            if (i < 3) LOADP(bufA, 2 * i + 2);
            COMPUTE(bufB, 2 * i + 1);
        }
#undef LOADP
#undef COMPUTE
    }
    __syncthreads();

    const int c = tid & 127;
    const int t0 = c * 32;
    const bool isB = tid >= 128;

    // ---- phase 1: per-(chunk,dir) operator (L=32), store scalar stride-11 ----
    {
        UT M;
        if (!isB) {
            float4 e0 = RDLE(t0);
            if (c == 0) {
                M.m00 = e0.x; M.m11 = e0.y; M.m22 = e0.z; M.m33 = e0.w;
                M.m01 = NEGF; M.m02 = NEGF; M.m03 = NEGF; M.m12 = NEGF; M.m13 = NEGF; M.m23 = NEGF;
            } else {
                M.m00 = A.A00 + e0.x; M.m01 = A.A01 + e0.y; M.m02 = A.A02 + e0.z; M.m03 = NEGF;
                M.m11 = A.A11 + e0.y; M.m12 = A.A12 + e0.z; M.m13 = A.A13 + e0.w;
                M.m22 = A.A22 + e0.z; M.m23 = A.A23 + e0.w; M.m33 = e0.w;
            }
            #pragma unroll
            for (int k = 1; k < 32; ++k) fstep(M, A, RDLE(t0 + k));
            ut_renorm(M);
            ut_store11(U + L0F + c * 11, M);
        } else {
            M.m00 = 0.f; M.m11 = 0.f; M.m22 = 0.f; M.m33 = 0.f;
            M.m01 = NEGF; M.m02 = NEGF; M.m03 = NEGF; M.m12 = NEGF; M.m13 = NEGF; M.m23 = NEGF;
            int nst = (c == 127) ? 31 : 32;
            #pragma unroll
            for (int k = 0; k < 32; ++k) {
                if (k < nst) fstep(M, A, RDLE(t0 + 1 + k));
            }
            ut_renorm(M);
            ut_store11(U + L0B + c * 11, M);
        }
    }
    __syncthreads();

    // ---- phase 2a: compose L0 pairs -> L1 (64/dir) ----
    if (tid < 128) {
        int dir = tid >> 6;
        int i = tid & 63;
        const float* src = U + (dir ? L0B : L0F);
        float* dst = U + (dir ? L1B : L1F);
        UT P = ut_compose(ut_load11(src + (2 * i) * 11), ut_load11(src + (2 * i + 1) * 11));
        ut_renorm(P);
        ut_store11(dst + i * 11, P);
    }
    __syncthreads();

    // ---- phase 2b: compose L1 pairs -> L2 (32/dir) ----
    if (tid < 64) {
        int dir = tid >> 5;
        int i = tid & 31;
        const float* src = U + (dir ? L1B : L1F);
        float* dst = U + (dir ? L2B : L2F);
        UT P = ut_compose(ut_load11(src + (2 * i) * 11), ut_load11(src + (2 * i + 1) * 11));
        ut_renorm(P);
        ut_store11(dst + i * 11, P);
    }
    __syncthreads();

    // ---- phase 2c: two scalar serial scans over 32 L2-ops (fwd on wave0, bwd on wave1) ----
    if (tid == 0) {
        float i0 = initl[0], i1 = initl[1], i2 = initl[2], i3 = initl[3];
        float m = fmaxf(fmaxf(i0, i1), fmaxf(i2, i3));
        float lz = m + __logf(__expf(i0 - m) + __expf(i1 - m) + __expf(i2 - m) + __expf(i3 - m));
        float v0 = (i0 - lz) * LOG2E, v1 = (i1 - lz) * LOG2E;
        float v2 = (i2 - lz) * LOG2E, v3 = (i3 - lz) * LOG2E;
        for (int g = 0; g < 32; ++g) {
            U[SF + g * 4 + 0] = v0; U[SF + g * 4 + 1] = v1;
            U[SF + g * 4 + 2] = v2; U[SF + g * 4 + 3] = v3;
            vecmat(v0, v1, v2, v3, U + L2F + g * 11);
        }
    } else if (tid == 64) {
        float u0 = 0.f, u1 = 0.f, u2 = 0.f, u3 = 0.f;
        for (int g = 31; g >= 0; --g) {
            U[SB + g * 4 + 0] = u0; U[SB + g * 4 + 1] = u1;
            U[SB + g * 4 + 2] = u2; U[SB + g * 4 + 3] = u3;
            matvec(U + L2B + g * 11, u0, u1, u2, u3);
        }
    }
    __syncthreads();

    // ---- phase 2d: downsweep to per-chunk boundaries, into registers ----
    float fa0, fa1, fa2, fa3;     // fwd: alpha boundary entering chunk c
    float fb0, fb1, fb2, fb3;     // bwd: beta boundary after chunk c
    {
        int g = c >> 2, r = c & 3;
        if (!isB) {
            fa0 = U[SF + g * 4 + 0]; fa1 = U[SF + g * 4 + 1];
            fa2 = U[SF + g * 4 + 2]; fa3 = U[SF + g * 4 + 3];
            if (r >= 2) vecmat(fa0, fa1, fa2, fa3, U + L1F + (2 * g) * 11);
            if (r & 1)  vecmat(fa0, fa1, fa2, fa3, U + L0F + (c - 1) * 11);
        } else {
            fb0 = U[SB + g * 4 + 0]; fb1 = U[SB + g * 4 + 1];
            fb2 = U[SB + g * 4 + 2]; fb3 = U[SB + g * 4 + 3];
            if (r <= 1)       matvec(U + L1B + (2 * g + 1) * 11, fb0, fb1, fb2, fb3);
            if ((r & 1) == 0) matvec(U + L0B + (c + 1) * 11, fb0, fb1, fb2, fb3);
        }
    }
    __syncthreads();   // op-tree reads done; abuf/bbuf may now clobber uni

    // ---- phase 3: replay + gamma.w emit (fwd waves 0,1 / bwd waves 2,3) ----
    float wv[SDIM][5];
    #pragma unroll
    for (int s = 0; s < SDIM; ++s)
        #pragma unroll
        for (int o = 0; o < 5; ++o) wv[s][o] = w[s * 5 + o];

    float* opb = out + (size_t)bidb * TDIM * 5;
    float vals[20];

    if (!isB) {
        float a0 = fa0, a1 = fa1, a2 = fa2, a3 = fa3;
        if (c == 0) {
            float4 e = RDLE(0);
            a0 += e.x; a1 += e.y; a2 += e.z; a3 += e.w;
            float mm = fmaxf(fmaxf(a0, a1), fmaxf(a2, a3));
            a0 -= mm; a1 -= mm; a2 -= mm; a3 -= mm;
        } else {
            ASTEP(RDLE(t0));
        }
        abuf[c * 17 + 0] = make_float4(a0, a1, a2, a3);
        #pragma unroll
        for (int k = 1; k < 16; ++k) {
            ASTEP(RDLE(t0 + k));
            abuf[c * 17 + k] = make_float4(a0, a1, a2, a3);
        }
        __syncthreads();
        float b0, b1, b2, b3;
        #pragma unroll
        for (int g = 4; g < 8; ++g) {
            #pragma unroll
            for (int q = 0; q < 4; ++q) {
                int k = g * 4 + q;
                ASTEP(RDLE(t0 + k));
                float4 bv = bbuf[c * 17 + (k - 16)];
                b0 = bv.x; b1 = bv.y; b2 = bv.z; b3 = bv.w;
                float4 av = make_float4(a0, a1, a2, a3);
                GEMIT(av, q);
            }
            float4* vo = reinterpret_cast<float4*>(opb + (size_t)(t0 + g * 4) * 5);
            vo[0] = make_float4(vals[0],  vals[1],  vals[2],  vals[3]);
            vo[1] = make_float4(vals[4],  vals[5],  vals[6],  vals[7]);
            vo[2] = make_float4(vals[8],  vals[9],  vals[10], vals[11]);
            vo[3] = make_float4(vals[12], vals[13], vals[14], vals[15]);
            vo[4] = make_float4(vals[16], vals[17], vals[18], vals[19]);
        }
    } else {
        float b0 = fb0, b1 = fb1, b2 = fb2, b3 = fb3;
        bool lastc = (c == 127);
        #pragma unroll
        for (int k = 31; k >= 16; --k) {
            if (!(lastc && k == 31)) BSTEP(RDLE(t0 + 1 + k));
            bbuf[c * 17 + (k - 16)] = make_float4(b0, b1, b2, b3);
        }
        __syncthreads();
        #pragma unroll
        for (int g = 3; g >= 0; --g) {
            #pragma unroll
            for (int q = 3; q >= 0; --q) {
                int k = g * 4 + q;
                BSTEP(RDLE(t0 + 1 + k));
                float4 av = abuf[c * 17 + k];
                GEMIT(av, q);
            }
            float4* vo = reinterpret_cast<float4*>(opb + (size_t)(t0 + g * 4) * 5);
            vo[0] = make_float4(vals[0],  vals[1],  vals[2],  vals[3]);
            vo[1] = make_float4(vals[4],  vals[5],  vals[6],  vals[7]);
            vo[2] = make_float4(vals[8],  vals[9],  vals[10], vals[11]);
            vo[3] = make_float4(vals[12], vals[13], vals[14], vals[15]);
            vo[4] = make_float4(vals[16], vals[17], vals[18], vals[19]);
        }
    }
}

extern "C" void kernel_launch(void* const* d_in, const int* in_sizes, int n_in,
                              void* d_out, int out_size, void* d_ws, size_t ws_size,
                              hipStream_t stream) {
    const float* x     = (const float*)d_in[0];
    const float* emit  = (const float*)d_in[1];
    const float* trans = (const float*)d_in[2];
    const float* initl = (const float*)d_in[3];
    const float* w     = (const float*)d_in[4];
    float* out = (float*)d_out;

    hipLaunchKernelGGL(fused_kernel, dim3(BDIM), dim3(256), 0, stream,
                       x, emit, trans, initl, w, out);
}